// Round 3
// baseline (1219.341 us; speedup 1.0000x reference)
//
#include <hip/hip_runtime.h>
#include <hip/hip_bf16.h>
#include <math.h>

#define B_   32
#define S_   2048
#define H_   1024
#define K2H  2048           // 2H, GEMM K
#define M_TOT (B_*S_)       // 65536

typedef __attribute__((ext_vector_type(8))) short bf16x8;
typedef __attribute__((ext_vector_type(4))) float f32x4;

__device__ __forceinline__ short f2bf(float f) {
    union { float f; unsigned u; } c; c.f = f;
    unsigned u = c.u;
    unsigned r = u + 0x7FFFu + ((u >> 16) & 1u);
    return (short)(r >> 16);
}

// ---- convert W_w[:, :2048] -> bf16 w1[1024][2048] ----
__global__ void convert_w1(const float* __restrict__ W, short* __restrict__ w1) {
    int idx = blockIdx.x * blockDim.x + threadIdx.x;   // 524288 threads, 4 elems each
    int e = idx * 4;
    int h = e >> 11;
    int k = e & 2047;
    float4 v = *reinterpret_cast<const float4*>(W + (size_t)h * 3072 + k);
    short4 o;
    o.x = f2bf(v.x); o.y = f2bf(v.y); o.z = f2bf(v.z); o.w = f2bf(v.w);
    *reinterpret_cast<short4*>(w1 + (size_t)h * 2048 + k) = o;
}

// ---- dproj[b][h] = dec[b,:] . W_w[h, 2048:3072] + W_b[h]  (fp32) ----
__global__ void dproj_kernel(const float* __restrict__ dec, const float* __restrict__ W,
                             const float* __restrict__ Wb, float* __restrict__ dproj) {
    __shared__ float dl[1024];
    int b = blockIdx.x >> 4;          // 32 b
    int hc = blockIdx.x & 15;         // 16 h-chunks of 64
    int t = threadIdx.x;
    for (int i = t; i < 1024; i += 256) dl[i] = dec[b * 1024 + i];
    __syncthreads();
    int wv = t >> 6, lane = t & 63;
    for (int it = 0; it < 16; ++it) {
        int h = hc * 64 + wv * 16 + it;
        const float* wrow = W + (size_t)h * 3072 + 2048;
        float acc = 0.f;
        for (int j = lane; j < 1024; j += 64) acc += dl[j] * wrow[j];
        for (int m = 32; m >= 1; m >>= 1) acc += __shfl_xor(acc, m);
        if (lane == 0) dproj[b * 1024 + h] = acc + Wb[h];
    }
}

// ---- fused GEMM: scores[m] += sum_h Vw[h]*tanh(enc_row(m).W1[h] + dproj[b][h]) ----
#define BM 128
#define BN 128
#define BK 64
#define LDA 72   // padded LDS stride (bf16 elems): 144 B rows -> 2-way-max bank alias

__launch_bounds__(256, 2)
__global__ void fused_gemm(const float* __restrict__ enc, const short* __restrict__ w1,
                           const float* __restrict__ dproj, const float* __restrict__ Vw,
                           float* __restrict__ scores) {
    __shared__ short As[BM * LDA];
    __shared__ short Bs[BN * LDA];
    int nt = blockIdx.x & 7;       // 8 n-tiles (H/BN)
    int mt = blockIdx.x >> 3;      // 512 m-tiles
    int m0 = mt * BM, n0 = nt * BN;
    int t = threadIdx.x, lane = t & 63, wv = t >> 6;
    int wm = wv >> 1, wn = wv & 1;

    // A staging: 128x64 fp32 -> bf16. thread: row t>>4 (+p*16), 4 floats at (t&15)*4
    int ar = t >> 4;
    int ac = (t & 15) * 4;
    const float* aptr = enc + (size_t)(m0 + ar) * K2H + ac;
    // B staging: 128x64 bf16 from w1. thread: row t>>3 (+p*32), 8 bf16 at (t&7)*8
    int br = t >> 3;
    int bc = (t & 7) * 8;
    const short* bptr = w1 + (size_t)(n0 + br) * K2H + bc;

    float4 areg[8];
    int4 breg[4];

    auto loadA = [&](int kt) {
#pragma unroll
        for (int p = 0; p < 8; ++p)
            areg[p] = *reinterpret_cast<const float4*>(aptr + (size_t)(p * 16) * K2H + kt * BK);
    };
    auto loadB = [&](int kt) {
#pragma unroll
        for (int p = 0; p < 4; ++p)
            breg[p] = *reinterpret_cast<const int4*>(bptr + (size_t)(p * 32) * K2H + kt * BK);
    };

    f32x4 acc[4][4] = {};

    loadA(0); loadB(0);
    const int NT = K2H / BK;   // 32
    for (int kt = 0; kt < NT; ++kt) {
        __syncthreads();
#pragma unroll
        for (int p = 0; p < 8; ++p) {
            short4 o;
            o.x = f2bf(areg[p].x); o.y = f2bf(areg[p].y);
            o.z = f2bf(areg[p].z); o.w = f2bf(areg[p].w);
            *reinterpret_cast<short4*>(&As[(ar + p * 16) * LDA + ac]) = o;
        }
#pragma unroll
        for (int p = 0; p < 4; ++p)
            *reinterpret_cast<int4*>(&Bs[(br + p * 32) * LDA + bc]) = breg[p];
        __syncthreads();
        if (kt + 1 < NT) { loadA(kt + 1); loadB(kt + 1); }
#pragma unroll
        for (int ks = 0; ks < 2; ++ks) {
            bf16x8 af[4], bfrag[4];
#pragma unroll
            for (int i = 0; i < 4; ++i)
                af[i] = *reinterpret_cast<const bf16x8*>(
                    &As[(wm * 64 + i * 16 + (lane & 15)) * LDA + ks * 32 + (lane >> 4) * 8]);
#pragma unroll
            for (int j = 0; j < 4; ++j)
                bfrag[j] = *reinterpret_cast<const bf16x8*>(
                    &Bs[(wn * 64 + j * 16 + (lane & 15)) * LDA + ks * 32 + (lane >> 4) * 8]);
#pragma unroll
            for (int i = 0; i < 4; ++i)
#pragma unroll
                for (int j = 0; j < 4; ++j)
                    acc[i][j] = __builtin_amdgcn_mfma_f32_16x16x32_bf16(af[i], bfrag[j], acc[i][j], 0, 0, 0);
        }
    }

    // epilogue: e = acc + dproj; part = Vw * tanh(e); reduce over h; atomic to scores
    int b = m0 >> 11;   // BM=128 divides 2048 -> uniform batch per block
    float dp[4], vv[4];
#pragma unroll
    for (int j = 0; j < 4; ++j) {
        int hg = n0 + wn * 64 + j * 16 + (lane & 15);
        dp[j] = dproj[b * 1024 + hg];
        vv[j] = Vw[hg];
    }
#pragma unroll
    for (int i = 0; i < 4; ++i) {
#pragma unroll
        for (int q = 0; q < 4; ++q) {
            float part = 0.f;
#pragma unroll
            for (int j = 0; j < 4; ++j)
                part += vv[j] * tanhf(acc[i][j][q] + dp[j]);
            part += __shfl_xor(part, 1);
            part += __shfl_xor(part, 2);
            part += __shfl_xor(part, 4);
            part += __shfl_xor(part, 8);
            if ((lane & 15) == 0) {
                int mg = m0 + wm * 64 + i * 16 + ((lane >> 4) << 2) + q;
                atomicAdd(&scores[mg], part);
            }
        }
    }
}

// ---- softmax over S per batch (mask-aware), in-place on scores ----
__global__ void softmax_kernel(const float* __restrict__ mask, float* __restrict__ scores) {
    int b = blockIdx.x;
    int t = threadIdx.x;
    __shared__ float red[8];
    __shared__ float red2[8];
    float v[8];
    float mx = -INFINITY;
#pragma unroll
    for (int k = 0; k < 8; ++k) {
        int s = t + k * 256;
        float x = scores[b * 2048 + s];
        float mk = mask[b * 2048 + s];
        x = (mk > 0.f) ? x : -INFINITY;
        v[k] = x;
        mx = fmaxf(mx, x);
    }
    int lane = t & 63, wv = t >> 6;
    for (int m = 32; m >= 1; m >>= 1) mx = fmaxf(mx, __shfl_xor(mx, m));
    if (lane == 0) red[wv] = mx;
    __syncthreads();
    mx = fmaxf(fmaxf(red[0], red[1]), fmaxf(red[2], red[3]));
    float sum = 0.f;
#pragma unroll
    for (int k = 0; k < 8; ++k) { v[k] = __expf(v[k] - mx); sum += v[k]; }
    for (int m = 32; m >= 1; m >>= 1) sum += __shfl_xor(sum, m);
    if (lane == 0) red2[wv] = sum;
    __syncthreads();
    sum = red2[0] + red2[1] + red2[2] + red2[3];
    float inv = 1.f / sum;
#pragma unroll
    for (int k = 0; k < 8; ++k) scores[b * 2048 + t + k * 256] = v[k] * inv;
}

// ---- context[b,d] = sum_s attn[b,s] * enc[b,s,d] ----
#define SCH 128    // s rows per block
#define NSC 16     // s chunks
__global__ void context_kernel(const float* __restrict__ enc, const float* __restrict__ attn,
                               float* __restrict__ out) {
    // grid: b(32) x dchunk(2) x schunk(16) = 1024 blocks
    int bid = blockIdx.x;
    int b = bid >> 5;
    int dchunk = (bid >> 4) & 1;
    int schunk = bid & 15;
    int t = threadIdx.x;
    __shared__ float aw[SCH];
    if (t < SCH) aw[t] = attn[b * 2048 + schunk * SCH + t];
    __syncthreads();
    int c = dchunk * 1024 + t * 4;
    const float* base = enc + (size_t)b * S_ * K2H + (size_t)(schunk * SCH) * K2H + c;
    float4 acc = {0.f, 0.f, 0.f, 0.f};
    for (int s = 0; s < SCH; ++s) {
        float w = aw[s];
        float4 v = *reinterpret_cast<const float4*>(base + (size_t)s * K2H);
        acc.x += w * v.x; acc.y += w * v.y; acc.z += w * v.z; acc.w += w * v.w;
    }
    float* o = out + b * 2048 + c;
    atomicAdd(o + 0, acc.x);
    atomicAdd(o + 1, acc.y);
    atomicAdd(o + 2, acc.z);
    atomicAdd(o + 3, acc.w);
}

extern "C" void kernel_launch(void* const* d_in, const int* in_sizes, int n_in,
                              void* d_out, int out_size, void* d_ws, size_t ws_size,
                              hipStream_t stream) {
    const float* enc  = (const float*)d_in[0];   // (B,S,2H)
    const float* mask = (const float*)d_in[1];   // (B,S,1)
    const float* dec  = (const float*)d_in[2];   // (1,B,H)
    const float* Ww   = (const float*)d_in[3];   // (H,3H)
    const float* Wb   = (const float*)d_in[4];   // (H,)
    const float* Vw   = (const float*)d_in[5];   // (1,H)
    // V_b (d_in[6]) is a constant added to all scores -> softmax-invariant, skip.
    float* out = (float*)d_out;

    char* ws = (char*)d_ws;
    short* w1     = (short*)ws;                              // 4 MB bf16 W1
    float* dproj  = (float*)(ws + (4u << 20));               // 128 KB
    float* scores = (float*)(ws + (4u << 20) + (128u << 10));// 256 KB

    hipMemsetAsync(scores, 0, M_TOT * sizeof(float), stream);
    hipMemsetAsync(out, 0, (size_t)out_size * sizeof(float), stream);

    convert_w1<<<2048, 256, 0, stream>>>(Ww, w1);
    dproj_kernel<<<512, 256, 0, stream>>>(dec, Ww, Wb, dproj);
    fused_gemm<<<4096, 256, 0, stream>>>(enc, w1, dproj, Vw, scores);
    softmax_kernel<<<32, 256, 0, stream>>>(mask, scores);
    context_kernel<<<1024, 256, 0, stream>>>(enc, scores, out);
}

// Round 4
// 1053.022 us; speedup vs baseline: 1.1579x; 1.1579x over previous
//
#include <hip/hip_runtime.h>
#include <hip/hip_bf16.h>
#include <math.h>

#define B_   32
#define S_   2048
#define H_   1024
#define K2H  2048           // 2H, GEMM K
#define M_TOT (B_*S_)       // 65536

typedef __attribute__((ext_vector_type(8))) short bf16x8;
typedef __attribute__((ext_vector_type(4))) float f32x4;

__device__ __forceinline__ short f2bf(float f) {
    union { float f; unsigned u; } c; c.f = f;
    unsigned u = c.u;
    unsigned r = u + 0x7FFFu + ((u >> 16) & 1u);
    return (short)(r >> 16);
}

// ---- convert W_w[:, :2048] -> bf16 w1[1024][2048] ----
__global__ void convert_w1(const float* __restrict__ W, short* __restrict__ w1) {
    int idx = blockIdx.x * blockDim.x + threadIdx.x;   // 524288 threads, 4 elems each
    int e = idx * 4;
    int h = e >> 11;
    int k = e & 2047;
    float4 v = *reinterpret_cast<const float4*>(W + (size_t)h * 3072 + k);
    short4 o;
    o.x = f2bf(v.x); o.y = f2bf(v.y); o.z = f2bf(v.z); o.w = f2bf(v.w);
    *reinterpret_cast<short4*>(w1 + (size_t)h * 2048 + k) = o;
}

// ---- dproj[b][h] = dec[b,:] . W_w[h, 2048:3072] + W_b[h]  (fp32) ----
__global__ void dproj_kernel(const float* __restrict__ dec, const float* __restrict__ W,
                             const float* __restrict__ Wb, float* __restrict__ dproj) {
    __shared__ float dl[1024];
    int b = blockIdx.x >> 4;          // 32 b
    int hc = blockIdx.x & 15;         // 16 h-chunks of 64
    int t = threadIdx.x;
    for (int i = t; i < 1024; i += 256) dl[i] = dec[b * 1024 + i];
    __syncthreads();
    int wv = t >> 6, lane = t & 63;
    for (int it = 0; it < 16; ++it) {
        int h = hc * 64 + wv * 16 + it;
        const float* wrow = W + (size_t)h * 3072 + 2048;
        float acc = 0.f;
        for (int j = lane; j < 1024; j += 64) acc += dl[j] * wrow[j];
        for (int m = 32; m >= 1; m >>= 1) acc += __shfl_xor(acc, m);
        if (lane == 0) dproj[b * 1024 + h] = acc + Wb[h];
    }
}

// ---- fused GEMM: scores_p[nt*2+wn][m] = sum_{h in chunk} Vw[h]*tanh(enc.W1 + dproj) ----
#define BM 128
#define BN 128
#define BK 64
#define LDA 72   // padded LDS stride (bf16 elems)

__launch_bounds__(256, 2)
__global__ void fused_gemm(const float* __restrict__ enc, const short* __restrict__ w1,
                           const float* __restrict__ dproj, const float* __restrict__ Vw,
                           float* __restrict__ scores_p) {
    __shared__ short As[BM * LDA];
    __shared__ short Bs[BN * LDA];
    // XCD-locality decode: assume XCD = blockIdx % 8 (round-robin dispatch).
    // All 8 n-tiles of one m-slab get the same XCD and consecutive in-XCD order
    // -> per-K-stripe L2 reuse of the 1 MB enc slab.
    int bid = blockIdx.x;
    int x  = bid & 7;
    int r  = bid >> 3;
    int nt = r & 7;                    // 8 n-tiles (H/BN)
    int mt = ((r >> 3) << 3) | x;      // 512 m-tiles, mt%8 == XCD
    int m0 = mt * BM, n0 = nt * BN;
    int t = threadIdx.x, lane = t & 63, wv = t >> 6;
    int wm = wv >> 1, wn = wv & 1;

    // A staging: 128x64 fp32 -> bf16. thread: row t>>4 (+p*16), 4 floats at (t&15)*4
    int ar = t >> 4;
    int ac = (t & 15) * 4;
    const float* aptr = enc + (size_t)(m0 + ar) * K2H + ac;
    // B staging: 128x64 bf16 from w1. thread: row t>>3 (+p*32), 8 bf16 at (t&7)*8
    int br = t >> 3;
    int bc = (t & 7) * 8;
    const short* bptr = w1 + (size_t)(n0 + br) * K2H + bc;

    float4 areg[8];
    int4 breg[4];

    auto loadA = [&](int kt) {
#pragma unroll
        for (int p = 0; p < 8; ++p)
            areg[p] = *reinterpret_cast<const float4*>(aptr + (size_t)(p * 16) * K2H + kt * BK);
    };
    auto loadB = [&](int kt) {
#pragma unroll
        for (int p = 0; p < 4; ++p)
            breg[p] = *reinterpret_cast<const int4*>(bptr + (size_t)(p * 32) * K2H + kt * BK);
    };

    f32x4 acc[4][4] = {};

    loadA(0); loadB(0);
    const int NT = K2H / BK;   // 32
    for (int kt = 0; kt < NT; ++kt) {
        __syncthreads();
#pragma unroll
        for (int p = 0; p < 8; ++p) {
            short4 o;
            o.x = f2bf(areg[p].x); o.y = f2bf(areg[p].y);
            o.z = f2bf(areg[p].z); o.w = f2bf(areg[p].w);
            *reinterpret_cast<short4*>(&As[(ar + p * 16) * LDA + ac]) = o;
        }
#pragma unroll
        for (int p = 0; p < 4; ++p)
            *reinterpret_cast<int4*>(&Bs[(br + p * 32) * LDA + bc]) = breg[p];
        __syncthreads();
        if (kt + 1 < NT) { loadA(kt + 1); loadB(kt + 1); }
#pragma unroll
        for (int ks = 0; ks < 2; ++ks) {
            bf16x8 af[4], bfrag[4];
#pragma unroll
            for (int i = 0; i < 4; ++i)
                af[i] = *reinterpret_cast<const bf16x8*>(
                    &As[(wm * 64 + i * 16 + (lane & 15)) * LDA + ks * 32 + (lane >> 4) * 8]);
#pragma unroll
            for (int j = 0; j < 4; ++j)
                bfrag[j] = *reinterpret_cast<const bf16x8*>(
                    &Bs[(wn * 64 + j * 16 + (lane & 15)) * LDA + ks * 32 + (lane >> 4) * 8]);
#pragma unroll
            for (int i = 0; i < 4; ++i)
#pragma unroll
                for (int j = 0; j < 4; ++j)
                    acc[i][j] = __builtin_amdgcn_mfma_f32_16x16x32_bf16(af[i], bfrag[j], acc[i][j], 0, 0, 0);
        }
    }

    // epilogue: e = acc + dproj; part = Vw * tanh(e); reduce over h-chunk; plain store
    int b = m0 >> 11;   // BM=128 divides 2048 -> uniform batch per block
    float dp[4], vv[4];
#pragma unroll
    for (int j = 0; j < 4; ++j) {
        int hg = n0 + wn * 64 + j * 16 + (lane & 15);
        dp[j] = dproj[b * 1024 + hg];
        vv[j] = Vw[hg];
    }
    float* sp = scores_p + (size_t)(nt * 2 + wn) * M_TOT;
#pragma unroll
    for (int i = 0; i < 4; ++i) {
#pragma unroll
        for (int q = 0; q < 4; ++q) {
            float part = 0.f;
#pragma unroll
            for (int j = 0; j < 4; ++j)
                part += vv[j] * tanhf(acc[i][j][q] + dp[j]);
            part += __shfl_xor(part, 1);
            part += __shfl_xor(part, 2);
            part += __shfl_xor(part, 4);
            part += __shfl_xor(part, 8);
            if ((lane & 15) == 0) {
                int mg = m0 + wm * 64 + i * 16 + ((lane >> 4) << 2) + q;
                sp[mg] = part;   // unique writer per (nt,wn,mg) -> no atomics
            }
        }
    }
}

// ---- softmax over S per batch: sum 16 partials, mask, softmax -> attn ----
__global__ void softmax_kernel(const float* __restrict__ scores_p, const float* __restrict__ mask,
                               float* __restrict__ attn) {
    int b = blockIdx.x;
    int t = threadIdx.x;
    __shared__ float red[8];
    __shared__ float red2[8];
    float v[8];
    float mx = -INFINITY;
#pragma unroll
    for (int k = 0; k < 8; ++k) {
        int s = t + k * 256;
        float xv = 0.f;
#pragma unroll
        for (int p = 0; p < 16; ++p) xv += scores_p[(size_t)p * M_TOT + b * 2048 + s];
        float mk = mask[b * 2048 + s];
        xv = (mk > 0.f) ? xv : -INFINITY;
        v[k] = xv;
        mx = fmaxf(mx, xv);
    }
    int lane = t & 63, wv = t >> 6;
    for (int m = 32; m >= 1; m >>= 1) mx = fmaxf(mx, __shfl_xor(mx, m));
    if (lane == 0) red[wv] = mx;
    __syncthreads();
    mx = fmaxf(fmaxf(red[0], red[1]), fmaxf(red[2], red[3]));
    float sum = 0.f;
#pragma unroll
    for (int k = 0; k < 8; ++k) { v[k] = __expf(v[k] - mx); sum += v[k]; }
    for (int m = 32; m >= 1; m >>= 1) sum += __shfl_xor(sum, m);
    if (lane == 0) red2[wv] = sum;
    __syncthreads();
    sum = red2[0] + red2[1] + red2[2] + red2[3];
    float inv = 1.f / sum;
#pragma unroll
    for (int k = 0; k < 8; ++k) attn[b * 2048 + t + k * 256] = v[k] * inv;
}

// ---- context[b,d] = sum_s attn[b,s] * enc[b,s,d] ----
#define SCH 64     // s rows per block
__global__ void context_kernel(const float* __restrict__ enc, const float* __restrict__ attn,
                               float* __restrict__ out) {
    // grid: b(32) x dchunk(2) x schunk(32) = 2048 blocks
    int bid = blockIdx.x;
    int b = bid >> 6;
    int dchunk = (bid >> 5) & 1;
    int schunk = bid & 31;
    int t = threadIdx.x;
    __shared__ float aw[SCH];
    if (t < SCH) aw[t] = attn[b * 2048 + schunk * SCH + t];
    __syncthreads();
    int c = dchunk * 1024 + t * 4;
    const float* base = enc + (size_t)b * S_ * K2H + (size_t)(schunk * SCH) * K2H + c;
    float4 acc = {0.f, 0.f, 0.f, 0.f};
    for (int s = 0; s < SCH; ++s) {
        float w = aw[s];
        float4 v = *reinterpret_cast<const float4*>(base + (size_t)s * K2H);
        acc.x += w * v.x; acc.y += w * v.y; acc.z += w * v.z; acc.w += w * v.w;
    }
    float* o = out + b * 2048 + c;
    atomicAdd(o + 0, acc.x);
    atomicAdd(o + 1, acc.y);
    atomicAdd(o + 2, acc.z);
    atomicAdd(o + 3, acc.w);
}

extern "C" void kernel_launch(void* const* d_in, const int* in_sizes, int n_in,
                              void* d_out, int out_size, void* d_ws, size_t ws_size,
                              hipStream_t stream) {
    const float* enc  = (const float*)d_in[0];   // (B,S,2H)
    const float* mask = (const float*)d_in[1];   // (B,S,1)
    const float* dec  = (const float*)d_in[2];   // (1,B,H)
    const float* Ww   = (const float*)d_in[3];   // (H,3H)
    const float* Wb   = (const float*)d_in[4];   // (H,)
    const float* Vw   = (const float*)d_in[5];   // (1,H)
    // V_b (d_in[6]) is a constant added to all scores -> softmax-invariant, skip.
    float* out = (float*)d_out;

    char* ws = (char*)d_ws;
    short* w1       = (short*)ws;                               // 4 MB bf16 W1
    float* scores_p = (float*)(ws + (4u << 20));                // 16 x 65536 fp32 = 4 MB
    float* dproj    = (float*)(ws + (8u << 20));                // 128 KB
    float* attn     = (float*)(ws + (8u << 20) + (128u << 10)); // 256 KB

    hipMemsetAsync(out, 0, (size_t)out_size * sizeof(float), stream);

    convert_w1<<<2048, 256, 0, stream>>>(Ww, w1);
    dproj_kernel<<<512, 256, 0, stream>>>(dec, Ww, Wb, dproj);
    fused_gemm<<<4096, 256, 0, stream>>>(enc, w1, dproj, Vw, scores_p);
    softmax_kernel<<<32, 256, 0, stream>>>(scores_p, mask, attn);
    context_kernel<<<2048, 256, 0, stream>>>(enc, attn, out);
}

// Round 5
// 676.329 us; speedup vs baseline: 1.8029x; 1.5570x over previous
//
#include <hip/hip_runtime.h>
#include <hip/hip_bf16.h>
#include <math.h>

#define B_   32
#define S_   2048
#define H_   1024
#define K2H  2048           // 2H, GEMM K
#define M_TOT (B_*S_)       // 65536

typedef __attribute__((ext_vector_type(8))) short bf16x8;
typedef __attribute__((ext_vector_type(4))) float f32x4;

__device__ __forceinline__ short f2bf(float f) {
    union { float f; unsigned u; } c; c.f = f;
    unsigned u = c.u;
    unsigned r = u + 0x7FFFu + ((u >> 16) & 1u);
    return (short)(r >> 16);
}

// ---- convert enc (B,S,2H) fp32 -> bf16, 8 elems/thread ----
__global__ void convert_enc(const float* __restrict__ enc, short* __restrict__ encb) {
    size_t e = ((size_t)blockIdx.x * blockDim.x + threadIdx.x) * 8;
    float4 v0 = *reinterpret_cast<const float4*>(enc + e);
    float4 v1 = *reinterpret_cast<const float4*>(enc + e + 4);
    short s[8];
    s[0]=f2bf(v0.x); s[1]=f2bf(v0.y); s[2]=f2bf(v0.z); s[3]=f2bf(v0.w);
    s[4]=f2bf(v1.x); s[5]=f2bf(v1.y); s[6]=f2bf(v1.z); s[7]=f2bf(v1.w);
    *reinterpret_cast<int4*>(encb + e) = *reinterpret_cast<const int4*>(s);
}

// ---- convert W_w[:, :2048] -> bf16 w1[1024][2048] ----
__global__ void convert_w1(const float* __restrict__ W, short* __restrict__ w1) {
    int idx = blockIdx.x * blockDim.x + threadIdx.x;
    int e = idx * 4;
    int h = e >> 11;
    int k = e & 2047;
    float4 v = *reinterpret_cast<const float4*>(W + (size_t)h * 3072 + k);
    short4 o;
    o.x = f2bf(v.x); o.y = f2bf(v.y); o.z = f2bf(v.z); o.w = f2bf(v.w);
    *reinterpret_cast<short4*>(w1 + (size_t)h * 2048 + k) = o;
}

// ---- dproj[b][h] = dec[b,:] . W_w[h, 2048:3072] + W_b[h]  (fp32) ----
__global__ void dproj_kernel(const float* __restrict__ dec, const float* __restrict__ W,
                             const float* __restrict__ Wb, float* __restrict__ dproj) {
    __shared__ float dl[1024];
    int b = blockIdx.x >> 4;
    int hc = blockIdx.x & 15;
    int t = threadIdx.x;
    for (int i = t; i < 1024; i += 256) dl[i] = dec[b * 1024 + i];
    __syncthreads();
    int wv = t >> 6, lane = t & 63;
    for (int it = 0; it < 16; ++it) {
        int h = hc * 64 + wv * 16 + it;
        const float* wrow = W + (size_t)h * 3072 + 2048;
        float acc = 0.f;
        for (int j = lane; j < 1024; j += 64) acc += dl[j] * wrow[j];
        for (int m = 32; m >= 1; m >>= 1) acc += __shfl_xor(acc, m);
        if (lane == 0) dproj[b * 1024 + h] = acc + Wb[h];
    }
}

#define BM 128
#define BN 128
#define BK 64

__device__ __forceinline__ void gload16(const short* g, short* l) {
    __builtin_amdgcn_global_load_lds(
        (const __attribute__((address_space(1))) void*)g,
        (__attribute__((address_space(3))) void*)l,
        16, 0, 0);
}

// ---- m97-structure fused GEMM: global_load_lds staging of bf16 A,B ----
__launch_bounds__(256, 4)
__global__ void fused_gemm_lds(const short* __restrict__ encb, const short* __restrict__ w1,
                               const float* __restrict__ dproj, const float* __restrict__ Vw,
                               float* __restrict__ scores_p) {
    __shared__ short As[BM * BK];   // linear [128][64]
    __shared__ short Bs[BN * BK];
    int bid = blockIdx.x;
    int x  = bid & 7;
    int r  = bid >> 3;
    int nt = r & 7;
    int mt = ((r >> 3) << 3) | x;    // XCD-local m-slab
    int m0 = mt * BM, n0 = nt * BN;
    int t = threadIdx.x, lane = t & 63, wv = t >> 6;
    int wm = wv >> 1, wn = wv & 1;

    // staging geometry: issue p (0..3), wave wv: LDS elems [(p*4+wv)*512, +512)
    // lane l covers 8 elems at +l*8 -> row=(p*4+wv)*8 + (l>>3), col=(l&7)*8
    int srow = (lane >> 3);
    int scol = (lane & 7) * 8;
    const short* abase = encb + (size_t)m0 * K2H + scol;
    const short* bbase = w1 + (size_t)n0 * K2H + scol;

    f32x4 acc[4][4] = {};

    const int NT = K2H / BK;   // 32
    for (int kt = 0; kt < NT; ++kt) {
        __syncthreads();   // previous compute done before LDS overwrite
#pragma unroll
        for (int p = 0; p < 4; ++p) {
            int rr = (p * 4 + wv) * 8 + srow;
            gload16(abase + (size_t)rr * K2H + kt * BK, &As[(p * 4 + wv) * 512]);
            gload16(bbase + (size_t)rr * K2H + kt * BK, &Bs[(p * 4 + wv) * 512]);
        }
        __syncthreads();   // vmcnt(0) drain + barrier -> tiles ready
#pragma unroll
        for (int ks = 0; ks < 2; ++ks) {
            bf16x8 af[4], bfrag[4];
#pragma unroll
            for (int i = 0; i < 4; ++i)
                af[i] = *reinterpret_cast<const bf16x8*>(
                    &As[(wm * 64 + i * 16 + (lane & 15)) * BK + ks * 32 + (lane >> 4) * 8]);
#pragma unroll
            for (int j = 0; j < 4; ++j)
                bfrag[j] = *reinterpret_cast<const bf16x8*>(
                    &Bs[(wn * 64 + j * 16 + (lane & 15)) * BK + ks * 32 + (lane >> 4) * 8]);
#pragma unroll
            for (int i = 0; i < 4; ++i)
#pragma unroll
                for (int j = 0; j < 4; ++j)
                    acc[i][j] = __builtin_amdgcn_mfma_f32_16x16x32_bf16(af[i], bfrag[j], acc[i][j], 0, 0, 0);
        }
    }

    int b = m0 >> 11;
    float dp[4], vv[4];
#pragma unroll
    for (int j = 0; j < 4; ++j) {
        int hg = n0 + wn * 64 + j * 16 + (lane & 15);
        dp[j] = dproj[b * 1024 + hg];
        vv[j] = Vw[hg];
    }
    float* sp = scores_p + (size_t)(nt * 2 + wn) * M_TOT;
#pragma unroll
    for (int i = 0; i < 4; ++i) {
#pragma unroll
        for (int q = 0; q < 4; ++q) {
            float part = 0.f;
#pragma unroll
            for (int j = 0; j < 4; ++j)
                part += vv[j] * tanhf(acc[i][j][q] + dp[j]);
            part += __shfl_xor(part, 1);
            part += __shfl_xor(part, 2);
            part += __shfl_xor(part, 4);
            part += __shfl_xor(part, 8);
            if ((lane & 15) == 0) {
                int mg = m0 + wm * 64 + i * 16 + ((lane >> 4) << 2) + q;
                sp[mg] = part;
            }
        }
    }
}

// ---- fallback (round-4) reg-staged GEMM, used if ws too small ----
#define LDA 72
__launch_bounds__(256, 2)
__global__ void fused_gemm(const float* __restrict__ enc, const short* __restrict__ w1,
                           const float* __restrict__ dproj, const float* __restrict__ Vw,
                           float* __restrict__ scores_p) {
    __shared__ short As[BM * LDA];
    __shared__ short Bs[BN * LDA];
    int bid = blockIdx.x;
    int x  = bid & 7;
    int r  = bid >> 3;
    int nt = r & 7;
    int mt = ((r >> 3) << 3) | x;
    int m0 = mt * BM, n0 = nt * BN;
    int t = threadIdx.x, lane = t & 63, wv = t >> 6;
    int wm = wv >> 1, wn = wv & 1;

    int ar = t >> 4;
    int ac = (t & 15) * 4;
    const float* aptr = enc + (size_t)(m0 + ar) * K2H + ac;
    int br = t >> 3;
    int bc = (t & 7) * 8;
    const short* bptr = w1 + (size_t)(n0 + br) * K2H + bc;

    float4 areg[8];
    int4 breg[4];

    auto loadA = [&](int kt) {
#pragma unroll
        for (int p = 0; p < 8; ++p)
            areg[p] = *reinterpret_cast<const float4*>(aptr + (size_t)(p * 16) * K2H + kt * BK);
    };
    auto loadB = [&](int kt) {
#pragma unroll
        for (int p = 0; p < 4; ++p)
            breg[p] = *reinterpret_cast<const int4*>(bptr + (size_t)(p * 32) * K2H + kt * BK);
    };

    f32x4 acc[4][4] = {};

    loadA(0); loadB(0);
    const int NT = K2H / BK;
    for (int kt = 0; kt < NT; ++kt) {
        __syncthreads();
#pragma unroll
        for (int p = 0; p < 8; ++p) {
            short4 o;
            o.x = f2bf(areg[p].x); o.y = f2bf(areg[p].y);
            o.z = f2bf(areg[p].z); o.w = f2bf(areg[p].w);
            *reinterpret_cast<short4*>(&As[(ar + p * 16) * LDA + ac]) = o;
        }
#pragma unroll
        for (int p = 0; p < 4; ++p)
            *reinterpret_cast<int4*>(&Bs[(br + p * 32) * LDA + bc]) = breg[p];
        __syncthreads();
        if (kt + 1 < NT) { loadA(kt + 1); loadB(kt + 1); }
#pragma unroll
        for (int ks = 0; ks < 2; ++ks) {
            bf16x8 af[4], bfrag[4];
#pragma unroll
            for (int i = 0; i < 4; ++i)
                af[i] = *reinterpret_cast<const bf16x8*>(
                    &As[(wm * 64 + i * 16 + (lane & 15)) * LDA + ks * 32 + (lane >> 4) * 8]);
#pragma unroll
            for (int j = 0; j < 4; ++j)
                bfrag[j] = *reinterpret_cast<const bf16x8*>(
                    &Bs[(wn * 64 + j * 16 + (lane & 15)) * LDA + ks * 32 + (lane >> 4) * 8]);
#pragma unroll
            for (int i = 0; i < 4; ++i)
#pragma unroll
                for (int j = 0; j < 4; ++j)
                    acc[i][j] = __builtin_amdgcn_mfma_f32_16x16x32_bf16(af[i], bfrag[j], acc[i][j], 0, 0, 0);
        }
    }

    int b = m0 >> 11;
    float dp[4], vv[4];
#pragma unroll
    for (int j = 0; j < 4; ++j) {
        int hg = n0 + wn * 64 + j * 16 + (lane & 15);
        dp[j] = dproj[b * 1024 + hg];
        vv[j] = Vw[hg];
    }
    float* sp = scores_p + (size_t)(nt * 2 + wn) * M_TOT;
#pragma unroll
    for (int i = 0; i < 4; ++i) {
#pragma unroll
        for (int q = 0; q < 4; ++q) {
            float part = 0.f;
#pragma unroll
            for (int j = 0; j < 4; ++j)
                part += vv[j] * tanhf(acc[i][j][q] + dp[j]);
            part += __shfl_xor(part, 1);
            part += __shfl_xor(part, 2);
            part += __shfl_xor(part, 4);
            part += __shfl_xor(part, 8);
            if ((lane & 15) == 0) {
                int mg = m0 + wm * 64 + i * 16 + ((lane >> 4) << 2) + q;
                sp[mg] = part;
            }
        }
    }
}

// ---- softmax over S per batch: sum 16 partials, mask, softmax -> attn ----
__global__ void softmax_kernel(const float* __restrict__ scores_p, const float* __restrict__ mask,
                               float* __restrict__ attn) {
    int b = blockIdx.x;
    int t = threadIdx.x;
    __shared__ float red[8];
    __shared__ float red2[8];
    float v[8];
    float mx = -INFINITY;
#pragma unroll
    for (int k = 0; k < 8; ++k) {
        int s = t + k * 256;
        float xv = 0.f;
#pragma unroll
        for (int p = 0; p < 16; ++p) xv += scores_p[(size_t)p * M_TOT + b * 2048 + s];
        float mk = mask[b * 2048 + s];
        xv = (mk > 0.f) ? xv : -INFINITY;
        v[k] = xv;
        mx = fmaxf(mx, xv);
    }
    int lane = t & 63, wv = t >> 6;
    for (int m = 32; m >= 1; m >>= 1) mx = fmaxf(mx, __shfl_xor(mx, m));
    if (lane == 0) red[wv] = mx;
    __syncthreads();
    mx = fmaxf(fmaxf(red[0], red[1]), fmaxf(red[2], red[3]));
    float sum = 0.f;
#pragma unroll
    for (int k = 0; k < 8; ++k) { v[k] = __expf(v[k] - mx); sum += v[k]; }
    for (int m = 32; m >= 1; m >>= 1) sum += __shfl_xor(sum, m);
    if (lane == 0) red2[wv] = sum;
    __syncthreads();
    sum = red2[0] + red2[1] + red2[2] + red2[3];
    float inv = 1.f / sum;
#pragma unroll
    for (int k = 0; k < 8; ++k) attn[b * 2048 + t + k * 256] = v[k] * inv;
}

// ---- context[b,d] = sum_s attn[b,s] * enc[b,s,d] ----
#define SCH 64
__global__ void context_kernel(const float* __restrict__ enc, const float* __restrict__ attn,
                               float* __restrict__ out) {
    int bid = blockIdx.x;
    int b = bid >> 6;
    int dchunk = (bid >> 5) & 1;
    int schunk = bid & 31;
    int t = threadIdx.x;
    __shared__ float aw[SCH];
    if (t < SCH) aw[t] = attn[b * 2048 + schunk * SCH + t];
    __syncthreads();
    int c = dchunk * 1024 + t * 4;
    const float* base = enc + (size_t)b * S_ * K2H + (size_t)(schunk * SCH) * K2H + c;
    float4 acc = {0.f, 0.f, 0.f, 0.f};
    for (int s = 0; s < SCH; ++s) {
        float w = aw[s];
        float4 v = *reinterpret_cast<const float4*>(base + (size_t)s * K2H);
        acc.x += w * v.x; acc.y += w * v.y; acc.z += w * v.z; acc.w += w * v.w;
    }
    float* o = out + b * 2048 + c;
    atomicAdd(o + 0, acc.x);
    atomicAdd(o + 1, acc.y);
    atomicAdd(o + 2, acc.z);
    atomicAdd(o + 3, acc.w);
}

extern "C" void kernel_launch(void* const* d_in, const int* in_sizes, int n_in,
                              void* d_out, int out_size, void* d_ws, size_t ws_size,
                              hipStream_t stream) {
    const float* enc  = (const float*)d_in[0];   // (B,S,2H)
    const float* mask = (const float*)d_in[1];   // (B,S,1)
    const float* dec  = (const float*)d_in[2];   // (1,B,H)
    const float* Ww   = (const float*)d_in[3];   // (H,3H)
    const float* Wb   = (const float*)d_in[4];   // (H,)
    const float* Vw   = (const float*)d_in[5];   // (1,H)
    float* out = (float*)d_out;

    char* ws = (char*)d_ws;
    const size_t ENC_B = (size_t)M_TOT * K2H * 2;          // 256 MB bf16 enc
    const size_t need  = ENC_B + (4u << 20) + (4u << 20) + (1u << 20);

    hipMemsetAsync(out, 0, (size_t)out_size * sizeof(float), stream);

    if (ws_size >= need) {
        short* encb     = (short*)ws;
        short* w1       = (short*)(ws + ENC_B);
        float* scores_p = (float*)(ws + ENC_B + (4u << 20));
        float* dproj    = (float*)(ws + ENC_B + (8u << 20));
        float* attn     = (float*)(ws + ENC_B + (8u << 20) + (128u << 10));

        convert_enc<<<65536, 256, 0, stream>>>(enc, encb);
        convert_w1<<<2048, 256, 0, stream>>>(Ww, w1);
        dproj_kernel<<<512, 256, 0, stream>>>(dec, Ww, Wb, dproj);
        fused_gemm_lds<<<4096, 256, 0, stream>>>(encb, w1, dproj, Vw, scores_p);
        softmax_kernel<<<32, 256, 0, stream>>>(scores_p, mask, attn);
        context_kernel<<<2048, 256, 0, stream>>>(enc, attn, out);
    } else {
        short* w1       = (short*)ws;
        float* scores_p = (float*)(ws + (4u << 20));
        float* dproj    = (float*)(ws + (8u << 20));
        float* attn     = (float*)(ws + (8u << 20) + (128u << 10));

        convert_w1<<<2048, 256, 0, stream>>>(Ww, w1);
        dproj_kernel<<<512, 256, 0, stream>>>(dec, Ww, Wb, dproj);
        fused_gemm<<<4096, 256, 0, stream>>>(enc, w1, dproj, Vw, scores_p);
        softmax_kernel<<<32, 256, 0, stream>>>(scores_p, mask, attn);
        context_kernel<<<2048, 256, 0, stream>>>(enc, attn, out);
    }
}